// Round 5
// baseline (692.895 us; speedup 1.0000x reference)
//
#include <hip/hip_runtime.h>

#define N_NODES 100000
#define N_EDGES 1280000
#define F_IN    256
#define F_OUT   64

// ---------------- workspace layout (total ~46.9 MB) ----------------
// [0,4)            : int flag (1 = edge_index is int64, 0 = int32)
// [256, +400KB)    : deg   (N float)
// [+, +400KB)      : dinv  (N float)
// [+, +25.6MB)     : h     (N x 64 float)
// [+, +20.48MB)    : meta  (E x int4 {src,dst,norm,0})

// ---------------- dtype detection ----------------
// int64 little-endian: odd 32-bit words all 0 (indices < 2^31).
// int32: odd words are random node ids, essentially never all 0.
__global__ void k_detect(const int* __restrict__ ei32, int* __restrict__ flag) {
    int lane = threadIdx.x;                       // 64 threads, 1 wave
    int v = ei32[2 * lane + 1];
    unsigned long long b = __ballot(v == 0);
    if (lane == 0) flag[0] = (b == ~0ULL) ? 1 : 0;
}

__device__ __forceinline__ int load_idx(const void* ei, int f, long long pos) {
    if (f) return (int)((const long long*)ei)[pos];
    return ((const int*)ei)[pos];
}

// ---------------- degree ----------------
__global__ void k_zero_deg(float* __restrict__ deg) {
    int i = blockIdx.x * blockDim.x + threadIdx.x;
    if (i < N_NODES) deg[i] = 0.0f;
}

__global__ void k_deg(const void* __restrict__ ei, const float* __restrict__ ew,
                      const int* __restrict__ flag, float* __restrict__ deg) {
    int e = blockIdx.x * blockDim.x + threadIdx.x;
    if (e >= N_EDGES) return;
    int f = flag[0];
    int d = load_idx(ei, f, (long long)N_EDGES + e);
    atomicAdd(&deg[d], ew[e]);
}

__global__ void k_dinv(const float* __restrict__ deg, float* __restrict__ dinv) {
    int i = blockIdx.x * blockDim.x + threadIdx.x;
    if (i < N_NODES) {
        float dg = deg[i] + 1.0f;   // + self-loop weight 1; always > 0
        dinv[i] = rsqrtf(dg);
    }
}

// ---------------- edge meta: {src, dst, norm} ----------------
__global__ void k_meta(const void* __restrict__ ei, const float* __restrict__ ew,
                       const int* __restrict__ flag, const float* __restrict__ dinv,
                       int4* __restrict__ meta) {
    int e = blockIdx.x * blockDim.x + threadIdx.x;
    if (e >= N_EDGES) return;
    int f = flag[0];
    int s = load_idx(ei, f, e);
    int d = load_idx(ei, f, (long long)N_EDGES + e);
    float n = dinv[s] * ew[e] * dinv[d];
    meta[e] = make_int4(s, d, __float_as_int(n), 0);
}

// ---------------- GEMM: h = x @ W  (100000x256 @ 256x64) ----------------
// W transposed into LDS [64][260]; stride 260 % 32 == 4 -> b128 reads by 64
// lanes tile all 32 banks in the minimum 8 phases (bandwidth-optimal).
// 4 waves/block, 8 rows/wave; x rows read at wave-uniform addresses.
#define GROWS 8
#define GWAVES 4
__global__ __launch_bounds__(256, 2) void k_gemm(const float* __restrict__ x,
                                                 const float* __restrict__ w,
                                                 float* __restrict__ h) {
    __shared__ float Wt[F_OUT][F_IN + 4];
    for (int t = threadIdx.x; t < F_IN * F_OUT; t += 256) {
        int k = t >> 6, j = t & 63;
        Wt[j][k] = w[t];
    }
    __syncthreads();

    int lane = threadIdx.x & 63;
    int wv = __builtin_amdgcn_readfirstlane(threadIdx.x >> 6);
    int row0 = blockIdx.x * (GROWS * GWAVES) + wv * GROWS;   // 3125 * 32 = 100000
    const float* __restrict__ xr = x + (size_t)row0 * F_IN;

    float acc[GROWS];
#pragma unroll
    for (int r = 0; r < GROWS; ++r) acc[r] = 0.0f;

    for (int k4 = 0; k4 < F_IN; k4 += 4) {
        float4 wv4 = *(const float4*)&Wt[lane][k4];
#pragma unroll
        for (int r = 0; r < GROWS; ++r) {
            float4 xv = *(const float4*)(xr + r * F_IN + k4);
            acc[r] += xv.x * wv4.x + xv.y * wv4.y + xv.z * wv4.z + xv.w * wv4.w;
        }
    }

    float* hp = h + (size_t)row0 * F_OUT + lane;
#pragma unroll
    for (int r = 0; r < GROWS; ++r) hp[r * F_OUT] = acc[r];
}

// ---------------- out init: bias + self-loop term ----------------
__global__ void k_out_init(const float* __restrict__ h, const float* __restrict__ dinv,
                           const float* __restrict__ bias, float4* __restrict__ out4) {
    int i4 = blockIdx.x * blockDim.x + threadIdx.x;   // over N*16 float4s
    if (i4 >= N_NODES * (F_OUT / 4)) return;
    int node = i4 >> 4;
    int j = (i4 & 15) * 4;
    float dv = dinv[node];
    float sc = dv * dv;
    float4 hv = ((const float4*)h)[i4];
    float4 b = *(const float4*)&bias[j];
    out4[i4] = make_float4(b.x + sc * hv.x, b.y + sc * hv.y,
                           b.z + sc * hv.z, b.w + sc * hv.w);
}

// ---------------- edge aggregation: wave per edge, lane = feature ----------------
// 2-deep unrolled grid-stride loop: meta load for e+nw overlaps gather+atomic of e.
__global__ __launch_bounds__(256) void k_agg(const int4* __restrict__ meta,
                                             const float* __restrict__ h,
                                             float* __restrict__ out) {
    int lane = threadIdx.x & 63;
    int wid = blockIdx.x * (blockDim.x >> 6) + (threadIdx.x >> 6);
    int nw = gridDim.x * (blockDim.x >> 6);

    int e = wid;
    for (; e + nw < N_EDGES; e += 2 * nw) {
        int4 m0 = meta[e];
        int4 m1 = meta[e + nw];
        float h0 = h[(size_t)m0.x * F_OUT + lane];
        float h1 = h[(size_t)m1.x * F_OUT + lane];
        atomicAdd(&out[(size_t)m0.y * F_OUT + lane], __int_as_float(m0.z) * h0);
        atomicAdd(&out[(size_t)m1.y * F_OUT + lane], __int_as_float(m1.z) * h1);
    }
    if (e < N_EDGES) {
        int4 m = meta[e];
        float hv = h[(size_t)m.x * F_OUT + lane];
        atomicAdd(&out[(size_t)m.y * F_OUT + lane], __int_as_float(m.z) * hv);
    }
}

extern "C" void kernel_launch(void* const* d_in, const int* in_sizes, int n_in,
                              void* d_out, int out_size, void* d_ws, size_t ws_size,
                              hipStream_t stream) {
    const float* x    = (const float*)d_in[0];
    const float* w    = (const float*)d_in[1];
    const float* bias = (const float*)d_in[2];
    const void*  ei   = d_in[3];
    const float* ew   = (const float*)d_in[4];
    float* out = (float*)d_out;

    char* wsp = (char*)d_ws;
    int*   flag = (int*)wsp;
    float* deg  = (float*)(wsp + 256);
    float* dinv = (float*)(wsp + 256 + 400000);
    float* h    = (float*)(wsp + 256 + 800000);
    int4*  meta = (int4*)(wsp + 256 + 800000 + (size_t)N_NODES * F_OUT * 4);

    k_detect<<<1, 64, 0, stream>>>((const int*)ei, flag);
    k_zero_deg<<<(N_NODES + 255) / 256, 256, 0, stream>>>(deg);
    k_deg<<<(N_EDGES + 255) / 256, 256, 0, stream>>>(ei, ew, flag, deg);
    k_dinv<<<(N_NODES + 255) / 256, 256, 0, stream>>>(deg, dinv);
    k_gemm<<<N_NODES / (GROWS * GWAVES), 256, 0, stream>>>(x, w, h);
    k_meta<<<(N_EDGES + 255) / 256, 256, 0, stream>>>(ei, ew, flag, dinv, meta);
    k_out_init<<<(N_NODES * (F_OUT / 4) + 255) / 256, 256, 0, stream>>>(h, dinv, bias, (float4*)out);
    k_agg<<<4096, 256, 0, stream>>>(meta, h, out);
}

// Round 14
// 608.233 us; speedup vs baseline: 1.1392x; 1.1392x over previous
//
#include <hip/hip_runtime.h>

#define N_NODES 100000
#define N_EDGES 1280000
#define F_IN    256
#define F_OUT   64
#define NB_SCAN 391   // ceil(N_NODES/256)

// ---------------- workspace layout (~38.3 MB) ----------------
// flag(256B) | deg fN | dinv fN | cnt iN | rowstart i(N+1,pad) | cursor iN |
// bsum(2KB) | bbase(2KB) | h f[N*64] | sorted int2[E]

// ---------------- dtype detection ----------------
__global__ void k_detect(const int* __restrict__ ei32, int* __restrict__ flag) {
    int lane = threadIdx.x;                       // 64 threads, 1 wave
    int v = ei32[2 * lane + 1];
    unsigned long long b = __ballot(v == 0);
    if (lane == 0) flag[0] = (b == ~0ULL) ? 1 : 0;
}

__device__ __forceinline__ int load_idx(const void* ei, int f, long long pos) {
    if (f) return (int)((const long long*)ei)[pos];
    return ((const int*)ei)[pos];
}

// ---------------- zero deg + cnt ----------------
__global__ void k_zero(float* __restrict__ deg, int* __restrict__ cnt) {
    int i = blockIdx.x * blockDim.x + threadIdx.x;
    if (i < N_NODES) { deg[i] = 0.0f; cnt[i] = 0; }
}

// ---------------- weighted degree + histogram ----------------
__global__ void k_deg_cnt(const void* __restrict__ ei, const float* __restrict__ ew,
                          const int* __restrict__ flag, float* __restrict__ deg,
                          int* __restrict__ cnt) {
    int e = blockIdx.x * blockDim.x + threadIdx.x;
    if (e >= N_EDGES) return;
    int f = flag[0];
    int d = load_idx(ei, f, (long long)N_EDGES + e);
    atomicAdd(&deg[d], ew[e]);
    atomicAdd(&cnt[d], 1);
}

__global__ void k_dinv(const float* __restrict__ deg, float* __restrict__ dinv) {
    int i = blockIdx.x * blockDim.x + threadIdx.x;
    if (i < N_NODES) dinv[i] = rsqrtf(deg[i] + 1.0f);   // + self-loop w=1; always > 0
}

// ---------------- scan step 1: per-block exclusive scan of cnt ----------------
__global__ void k_scan1(const int* __restrict__ cnt, int* __restrict__ rowstart,
                        int* __restrict__ bsum) {
    __shared__ int s[256];
    int t = threadIdx.x;
    int i = blockIdx.x * 256 + t;
    int v = (i < N_NODES) ? cnt[i] : 0;
    s[t] = v; __syncthreads();
    for (int off = 1; off < 256; off <<= 1) {
        int a = s[t];
        int b = (t >= off) ? s[t - off] : 0;
        __syncthreads();
        s[t] = a + b; __syncthreads();
    }
    if (i < N_NODES) rowstart[i] = s[t] - v;      // exclusive
    if (t == 255) bsum[blockIdx.x] = s[255];      // block total
}

// ---------------- scan step 2: single-block scan of block sums ----------------
__global__ void k_scan2(int* __restrict__ bsum, int* __restrict__ bbase) {
    __shared__ int s[256];
    __shared__ int carry;
    int t = threadIdx.x;
    if (t == 0) carry = 0;
    __syncthreads();
    for (int base = 0; base < NB_SCAN; base += 256) {
        int i = base + t;
        int v = (i < NB_SCAN) ? bsum[i] : 0;
        s[t] = v; __syncthreads();
        for (int off = 1; off < 256; off <<= 1) {
            int a = s[t];
            int b = (t >= off) ? s[t - off] : 0;
            __syncthreads();
            s[t] = a + b; __syncthreads();
        }
        if (i < NB_SCAN) bbase[i] = carry + s[t] - v;
        __syncthreads();
        if (t == 255) carry += s[255];
        __syncthreads();
    }
}

// ---------------- scan step 3: add block base; init cursor ----------------
__global__ void k_scan3(int* __restrict__ rowstart, const int* __restrict__ bbase,
                        int* __restrict__ cursor) {
    int i = blockIdx.x * blockDim.x + threadIdx.x;
    if (i < N_NODES) {
        int r = rowstart[i] + bbase[i >> 8];
        rowstart[i] = r;
        cursor[i] = r;
    }
    if (i == 0) rowstart[N_NODES] = N_EDGES;
}

// ---------------- scatter: edges -> dst-sorted {src, norm} ----------------
__global__ void k_scatter(const void* __restrict__ ei, const float* __restrict__ ew,
                          const int* __restrict__ flag, const float* __restrict__ dinv,
                          int* __restrict__ cursor, int2* __restrict__ sorted) {
    int e = blockIdx.x * blockDim.x + threadIdx.x;
    if (e >= N_EDGES) return;
    int f = flag[0];
    int s = load_idx(ei, f, e);
    int d = load_idx(ei, f, (long long)N_EDGES + e);
    float n = dinv[s] * ew[e] * dinv[d];
    int pos = atomicAdd(&cursor[d], 1);
    sorted[pos] = make_int2(s, __float_as_int(n));
}

// ---------------- GEMM: h = x @ W (unchanged from R5 baseline) ----------------
#define GROWS 8
#define GWAVES 4
__global__ __launch_bounds__(256, 2) void k_gemm(const float* __restrict__ x,
                                                 const float* __restrict__ w,
                                                 float* __restrict__ h) {
    __shared__ float Wt[F_OUT][F_IN + 4];
    for (int t = threadIdx.x; t < F_IN * F_OUT; t += 256) {
        int k = t >> 6, j = t & 63;
        Wt[j][k] = w[t];
    }
    __syncthreads();

    int lane = threadIdx.x & 63;
    int wv = __builtin_amdgcn_readfirstlane(threadIdx.x >> 6);
    int row0 = blockIdx.x * (GROWS * GWAVES) + wv * GROWS;   // 3125 * 32 = 100000
    const float* __restrict__ xr = x + (size_t)row0 * F_IN;

    float acc[GROWS];
#pragma unroll
    for (int r = 0; r < GROWS; ++r) acc[r] = 0.0f;

    for (int k4 = 0; k4 < F_IN; k4 += 4) {
        float4 wv4 = *(const float4*)&Wt[lane][k4];
#pragma unroll
        for (int r = 0; r < GROWS; ++r) {
            float4 xv = *(const float4*)(xr + r * F_IN + k4);
            acc[r] += xv.x * wv4.x + xv.y * wv4.y + xv.z * wv4.z + xv.w * wv4.w;
        }
    }

    float* hp = h + (size_t)row0 * F_OUT + lane;
#pragma unroll
    for (int r = 0; r < GROWS; ++r) hp[r * F_OUT] = acc[r];
}

// ---------------- aggregation: wave per node, atomic-free, fused epilogue ----------------
__global__ __launch_bounds__(256) void k_agg2(const int2* __restrict__ sorted,
                                              const int* __restrict__ rowstart,
                                              const float* __restrict__ h,
                                              const float* __restrict__ dinv,
                                              const float* __restrict__ bias,
                                              float* __restrict__ out) {
    int lane = threadIdx.x & 63;
    int wid = blockIdx.x * (blockDim.x >> 6) + (threadIdx.x >> 6);
    int nw = gridDim.x * (blockDim.x >> 6);
    float bv = bias[lane];
    for (int n = wid; n < N_NODES; n += nw) {
        int beg = rowstart[n], end = rowstart[n + 1];
        float acc = 0.0f;
        int e = beg;
        for (; e + 1 < end; e += 2) {           // 2 indep gather chains
            int2 m0 = sorted[e];
            int2 m1 = sorted[e + 1];
            float h0 = h[(size_t)m0.x * F_OUT + lane];
            float h1 = h[(size_t)m1.x * F_OUT + lane];
            acc += __int_as_float(m0.y) * h0 + __int_as_float(m1.y) * h1;
        }
        if (e < end) {
            int2 m = sorted[e];
            acc += __int_as_float(m.y) * h[(size_t)m.x * F_OUT + lane];
        }
        float dv = dinv[n];
        out[(size_t)n * F_OUT + lane] = acc + bv + dv * dv * h[(size_t)n * F_OUT + lane];
    }
}

extern "C" void kernel_launch(void* const* d_in, const int* in_sizes, int n_in,
                              void* d_out, int out_size, void* d_ws, size_t ws_size,
                              hipStream_t stream) {
    const float* x    = (const float*)d_in[0];
    const float* w    = (const float*)d_in[1];
    const float* bias = (const float*)d_in[2];
    const void*  ei   = d_in[3];
    const float* ew   = (const float*)d_in[4];
    float* out = (float*)d_out;

    char* p = (char*)d_ws;
    int*   flag     = (int*)p;                       p += 256;
    float* deg      = (float*)p;                     p += 400000;
    float* dinv     = (float*)p;                     p += 400000;
    int*   cnt      = (int*)p;                       p += 400000;
    int*   rowstart = (int*)p;                       p += 400128;   // N+1, padded
    int*   cursor   = (int*)p;                       p += 400000;
    int*   bsum     = (int*)p;                       p += 2048;
    int*   bbase    = (int*)p;                       p += 2048;
    float* h        = (float*)p;                     p += (size_t)N_NODES * F_OUT * 4;
    int2*  sorted   = (int2*)p;                      // E * 8 B

    k_detect <<<1, 64, 0, stream>>>((const int*)ei, flag);
    k_zero   <<<(N_NODES + 255) / 256, 256, 0, stream>>>(deg, cnt);
    k_deg_cnt<<<(N_EDGES + 255) / 256, 256, 0, stream>>>(ei, ew, flag, deg, cnt);
    k_dinv   <<<(N_NODES + 255) / 256, 256, 0, stream>>>(deg, dinv);
    k_gemm   <<<N_NODES / (GROWS * GWAVES), 256, 0, stream>>>(x, w, h);
    k_scan1  <<<NB_SCAN, 256, 0, stream>>>(cnt, rowstart, bsum);
    k_scan2  <<<1, 256, 0, stream>>>(bsum, bbase);
    k_scan3  <<<(N_NODES + 255) / 256, 256, 0, stream>>>(rowstart, bbase, cursor);
    k_scatter<<<(N_EDGES + 255) / 256, 256, 0, stream>>>(ei, ew, flag, dinv, cursor, sorted);
    k_agg2   <<<2048, 256, 0, stream>>>(sorted, rowstart, h, dinv, bias, out);
}

// Round 17
// 471.531 us; speedup vs baseline: 1.4695x; 1.2899x over previous
//
#include <hip/hip_runtime.h>

#define N_NODES 100000
#define N_EDGES 1280000
#define F_IN    256
#define F_OUT   64
#define NB_SCAN 391   // ceil(N_NODES/256)

// ---------------- workspace layout (~38.3 MB) ----------------
// flag(256B) | deg fN | dinv fN | cnt iN | rowstart i(N+1,pad) | cursor iN |
// bsum(2KB) | bbase(2KB) | h f[N*64] | sorted int2[E]

// ---------------- dtype detection ----------------
__global__ void k_detect(const int* __restrict__ ei32, int* __restrict__ flag) {
    int lane = threadIdx.x;                       // 64 threads, 1 wave
    int v = ei32[2 * lane + 1];
    unsigned long long b = __ballot(v == 0);
    if (lane == 0) flag[0] = (b == ~0ULL) ? 1 : 0;
}

__device__ __forceinline__ int load_idx(const void* ei, int f, long long pos) {
    if (f) return (int)((const long long*)ei)[pos];
    return ((const int*)ei)[pos];
}

// ---------------- zero deg + cnt ----------------
__global__ void k_zero(float* __restrict__ deg, int* __restrict__ cnt) {
    int i = blockIdx.x * blockDim.x + threadIdx.x;
    if (i < N_NODES) { deg[i] = 0.0f; cnt[i] = 0; }
}

// ---------------- weighted degree + histogram ----------------
__global__ void k_deg_cnt(const void* __restrict__ ei, const float* __restrict__ ew,
                          const int* __restrict__ flag, float* __restrict__ deg,
                          int* __restrict__ cnt) {
    int e = blockIdx.x * blockDim.x + threadIdx.x;
    if (e >= N_EDGES) return;
    int f = flag[0];
    int d = load_idx(ei, f, (long long)N_EDGES + e);
    atomicAdd(&deg[d], ew[e]);
    atomicAdd(&cnt[d], 1);
}

__global__ void k_dinv(const float* __restrict__ deg, float* __restrict__ dinv) {
    int i = blockIdx.x * blockDim.x + threadIdx.x;
    if (i < N_NODES) dinv[i] = rsqrtf(deg[i] + 1.0f);   // + self-loop w=1; always > 0
}

// ---------------- scan step 1: per-block exclusive scan of cnt ----------------
__global__ void k_scan1(const int* __restrict__ cnt, int* __restrict__ rowstart,
                        int* __restrict__ bsum) {
    __shared__ int s[256];
    int t = threadIdx.x;
    int i = blockIdx.x * 256 + t;
    int v = (i < N_NODES) ? cnt[i] : 0;
    s[t] = v; __syncthreads();
    for (int off = 1; off < 256; off <<= 1) {
        int a = s[t];
        int b = (t >= off) ? s[t - off] : 0;
        __syncthreads();
        s[t] = a + b; __syncthreads();
    }
    if (i < N_NODES) rowstart[i] = s[t] - v;      // exclusive
    if (t == 255) bsum[blockIdx.x] = s[255];      // block total
}

// ---------------- scan step 2: single-block scan of block sums ----------------
__global__ void k_scan2(int* __restrict__ bsum, int* __restrict__ bbase) {
    __shared__ int s[256];
    __shared__ int carry;
    int t = threadIdx.x;
    if (t == 0) carry = 0;
    __syncthreads();
    for (int base = 0; base < NB_SCAN; base += 256) {
        int i = base + t;
        int v = (i < NB_SCAN) ? bsum[i] : 0;
        s[t] = v; __syncthreads();
        for (int off = 1; off < 256; off <<= 1) {
            int a = s[t];
            int b = (t >= off) ? s[t - off] : 0;
            __syncthreads();
            s[t] = a + b; __syncthreads();
        }
        if (i < NB_SCAN) bbase[i] = carry + s[t] - v;
        __syncthreads();
        if (t == 255) carry += s[255];
        __syncthreads();
    }
}

// ---------------- scan step 3: add block base; init cursor ----------------
__global__ void k_scan3(int* __restrict__ rowstart, const int* __restrict__ bbase,
                        int* __restrict__ cursor) {
    int i = blockIdx.x * blockDim.x + threadIdx.x;
    if (i < N_NODES) {
        int r = rowstart[i] + bbase[i >> 8];
        rowstart[i] = r;
        cursor[i] = r;
    }
    if (i == 0) rowstart[N_NODES] = N_EDGES;
}

// ---------------- scatter: edges -> dst-sorted {src, norm} ----------------
__global__ void k_scatter(const void* __restrict__ ei, const float* __restrict__ ew,
                          const int* __restrict__ flag, const float* __restrict__ dinv,
                          int* __restrict__ cursor, int2* __restrict__ sorted) {
    int e = blockIdx.x * blockDim.x + threadIdx.x;
    if (e >= N_EDGES) return;
    int f = flag[0];
    int s = load_idx(ei, f, e);
    int d = load_idx(ei, f, (long long)N_EDGES + e);
    float n = dinv[s] * ew[e] * dinv[d];
    int pos = atomicAdd(&cursor[d], 1);
    sorted[pos] = make_int2(s, __float_as_int(n));
}

// ---------------- GEMM: h = x @ W  (LDS-tiled, coalesced, reg-blocked) ----------------
// BM=128 rows/block, BK=64 k-chunk (4 chunks). 256 thr = 4 waves.
// Wave handles 32 rows x 64 cols; lane (rq=lane>>4, cq=lane&15) owns an
// 8x4 tile: rows wv*32 + rq + 4*i (interleave -> xs broadcast reads hit 16
// distinct banks, conflict-free), cols 4*cq..4*cq+3.
// LDS: xs[128][68] 34.8KB + ws[64][64] 16KB = 50KB -> 3 blocks/CU.
#define BM 128
#define BK 64
__global__ __launch_bounds__(256, 3) void k_gemm(const float* __restrict__ x,
                                                 const float* __restrict__ w,
                                                 float* __restrict__ h) {
    __shared__ float xs[BM][BK + 4];   // stride 68: 16B-aligned, rq*68%32=4rq
    __shared__ float ws[BK][F_OUT];    // stride 64

    const int t = threadIdx.x;
    const int lane = t & 63;
    const int wv = t >> 6;            // 0..3
    const int rq = lane >> 4;         // 0..3
    const int cq = lane & 15;         // 0..15
    const int row0 = blockIdx.x * BM;

    const int q  = t >> 4;            // 0..15 (staging row group)
    const int m4 = (t & 15) << 2;     // 0,4,..,60 (staging dword offset)

    float acc[8][4];
#pragma unroll
    for (int i = 0; i < 8; ++i)
#pragma unroll
        for (int c = 0; c < 4; ++c) acc[i][c] = 0.0f;

    for (int kk0 = 0; kk0 < F_IN; kk0 += BK) {
        // stage ws[64][64]: thread t loads rows k = 16j+q, 16B each
#pragma unroll
        for (int j = 0; j < 4; ++j) {
            int k = j * 16 + q;
            *(float4*)&ws[k][m4] = *(const float4*)&w[(size_t)(kk0 + k) * F_OUT + m4];
        }
        // stage xs[128][64]: thread t loads rows r = 16j+q, 16B each (coalesced)
#pragma unroll
        for (int j = 0; j < 8; ++j) {
            int r = j * 16 + q;
            int rg = row0 + r; if (rg > N_NODES - 1) rg = N_NODES - 1;  // clamp tail
            *(float4*)&xs[r][m4] = *(const float4*)&x[(size_t)rg * F_IN + kk0 + m4];
        }
        __syncthreads();

#pragma unroll 2
        for (int k4 = 0; k4 < BK; k4 += 4) {
            float4 w0 = *(const float4*)&ws[k4 + 0][cq * 4];
            float4 w1 = *(const float4*)&ws[k4 + 1][cq * 4];
            float4 w2 = *(const float4*)&ws[k4 + 2][cq * 4];
            float4 w3 = *(const float4*)&ws[k4 + 3][cq * 4];
#pragma unroll
            for (int i = 0; i < 8; ++i) {
                int r = wv * 32 + rq + 4 * i;
                float4 xv = *(const float4*)&xs[r][k4];
                acc[i][0] += xv.x * w0.x + xv.y * w1.x + xv.z * w2.x + xv.w * w3.x;
                acc[i][1] += xv.x * w0.y + xv.y * w1.y + xv.z * w2.y + xv.w * w3.y;
                acc[i][2] += xv.x * w0.z + xv.y * w1.z + xv.z * w2.z + xv.w * w3.z;
                acc[i][3] += xv.x * w0.w + xv.y * w1.w + xv.z * w2.w + xv.w * w3.w;
            }
        }
        __syncthreads();
    }

#pragma unroll
    for (int i = 0; i < 8; ++i) {
        int rg = row0 + wv * 32 + rq + 4 * i;
        if (rg < N_NODES)
            *(float4*)&h[(size_t)rg * F_OUT + cq * 4] =
                make_float4(acc[i][0], acc[i][1], acc[i][2], acc[i][3]);
    }
}

// ---------------- aggregation: wave per node, atomic-free, fused epilogue ----------------
__global__ __launch_bounds__(256) void k_agg2(const int2* __restrict__ sorted,
                                              const int* __restrict__ rowstart,
                                              const float* __restrict__ h,
                                              const float* __restrict__ dinv,
                                              const float* __restrict__ bias,
                                              float* __restrict__ out) {
    int lane = threadIdx.x & 63;
    int wid = blockIdx.x * (blockDim.x >> 6) + (threadIdx.x >> 6);
    int nw = gridDim.x * (blockDim.x >> 6);
    float bv = bias[lane];
    for (int n = wid; n < N_NODES; n += nw) {
        int beg = rowstart[n], end = rowstart[n + 1];
        float acc = 0.0f;
        int e = beg;
        for (; e + 1 < end; e += 2) {           // 2 indep gather chains
            int2 m0 = sorted[e];
            int2 m1 = sorted[e + 1];
            float h0 = h[(size_t)m0.x * F_OUT + lane];
            float h1 = h[(size_t)m1.x * F_OUT + lane];
            acc += __int_as_float(m0.y) * h0 + __int_as_float(m1.y) * h1;
        }
        if (e < end) {
            int2 m = sorted[e];
            acc += __int_as_float(m.y) * h[(size_t)m.x * F_OUT + lane];
        }
        float dv = dinv[n];
        out[(size_t)n * F_OUT + lane] = acc + bv + dv * dv * h[(size_t)n * F_OUT + lane];
    }
}

extern "C" void kernel_launch(void* const* d_in, const int* in_sizes, int n_in,
                              void* d_out, int out_size, void* d_ws, size_t ws_size,
                              hipStream_t stream) {
    const float* x    = (const float*)d_in[0];
    const float* w    = (const float*)d_in[1];
    const float* bias = (const float*)d_in[2];
    const void*  ei   = d_in[3];
    const float* ew   = (const float*)d_in[4];
    float* out = (float*)d_out;

    char* p = (char*)d_ws;
    int*   flag     = (int*)p;                       p += 256;
    float* deg      = (float*)p;                     p += 400000;
    float* dinv     = (float*)p;                     p += 400000;
    int*   cnt      = (int*)p;                       p += 400000;
    int*   rowstart = (int*)p;                       p += 400128;   // N+1, padded
    int*   cursor   = (int*)p;                       p += 400000;
    int*   bsum     = (int*)p;                       p += 2048;
    int*   bbase    = (int*)p;                       p += 2048;
    float* h        = (float*)p;                     p += (size_t)N_NODES * F_OUT * 4;
    int2*  sorted   = (int2*)p;                      // E * 8 B

    k_detect <<<1, 64, 0, stream>>>((const int*)ei, flag);
    k_zero   <<<(N_NODES + 255) / 256, 256, 0, stream>>>(deg, cnt);
    k_deg_cnt<<<(N_EDGES + 255) / 256, 256, 0, stream>>>(ei, ew, flag, deg, cnt);
    k_dinv   <<<(N_NODES + 255) / 256, 256, 0, stream>>>(deg, dinv);
    k_gemm   <<<(N_NODES + BM - 1) / BM, 256, 0, stream>>>(x, w, h);
    k_scan1  <<<NB_SCAN, 256, 0, stream>>>(cnt, rowstart, bsum);
    k_scan2  <<<1, 256, 0, stream>>>(bsum, bbase);
    k_scan3  <<<(N_NODES + 255) / 256, 256, 0, stream>>>(rowstart, bbase, cursor);
    k_scatter<<<(N_EDGES + 255) / 256, 256, 0, stream>>>(ei, ew, flag, dinv, cursor, sorted);
    k_agg2   <<<2048, 256, 0, stream>>>(sorted, rowstart, h, dinv, bias, out);
}

// Round 18
// 389.883 us; speedup vs baseline: 1.7772x; 1.2094x over previous
//
#include <hip/hip_runtime.h>

#define N_NODES 100000
#define N_EDGES 1280000
#define F_IN    256
#define F_OUT   64
#define NB_SCAN 391   // ceil(N_NODES/256)

// ---------------- workspace layout (~42.2 MB) ----------------
// flag(256B) | dinv fN | cnt iN | rowstart i(N+1,pad) | rank iE |
// h f[N*64] | sorted int2[E]

// ---------------- dtype detection ----------------
__global__ void k_detect(const int* __restrict__ ei32, int* __restrict__ flag) {
    int lane = threadIdx.x;                       // 64 threads, 1 wave
    int v = ei32[2 * lane + 1];
    unsigned long long b = __ballot(v == 0);
    if (lane == 0) flag[0] = (b == ~0ULL) ? 1 : 0;
}

__device__ __forceinline__ int load_idx(const void* ei, int f, long long pos) {
    if (f) return (int)((const long long*)ei)[pos];
    return ((const int*)ei)[pos];
}

// ---------------- zero cnt ----------------
__global__ void k_zero_cnt(int* __restrict__ cnt) {
    int i = blockIdx.x * blockDim.x + threadIdx.x;
    if (i < N_NODES) cnt[i] = 0;
}

// ---------------- rank pass: histogram + within-node rank (1.28M line-ops) ----------------
__global__ void k_rank(const void* __restrict__ ei, const int* __restrict__ flag,
                       int* __restrict__ cnt, int* __restrict__ rank) {
    int e = blockIdx.x * blockDim.x + threadIdx.x;
    if (e >= N_EDGES) return;
    int f = flag[0];
    int d = load_idx(ei, f, (long long)N_EDGES + e);
    rank[e] = atomicAdd(&cnt[d], 1);
}

// ---------------- scan step 1: per-block exclusive scan of cnt ----------------
__global__ void k_scan1(const int* __restrict__ cnt, int* __restrict__ rowstart,
                        int* __restrict__ bsum) {
    __shared__ int s[256];
    int t = threadIdx.x;
    int i = blockIdx.x * 256 + t;
    int v = (i < N_NODES) ? cnt[i] : 0;
    s[t] = v; __syncthreads();
    for (int off = 1; off < 256; off <<= 1) {
        int a = s[t];
        int b = (t >= off) ? s[t - off] : 0;
        __syncthreads();
        s[t] = a + b; __syncthreads();
    }
    if (i < N_NODES) rowstart[i] = s[t] - v;      // exclusive
    if (t == 255) bsum[blockIdx.x] = s[255];      // block total
}

// ---------------- scan step 2: single-block scan of block sums ----------------
__global__ void k_scan2(int* __restrict__ bsum, int* __restrict__ bbase) {
    __shared__ int s[256];
    __shared__ int carry;
    int t = threadIdx.x;
    if (t == 0) carry = 0;
    __syncthreads();
    for (int base = 0; base < NB_SCAN; base += 256) {
        int i = base + t;
        int v = (i < NB_SCAN) ? bsum[i] : 0;
        s[t] = v; __syncthreads();
        for (int off = 1; off < 256; off <<= 1) {
            int a = s[t];
            int b = (t >= off) ? s[t - off] : 0;
            __syncthreads();
            s[t] = a + b; __syncthreads();
        }
        if (i < NB_SCAN) bbase[i] = carry + s[t] - v;
        __syncthreads();
        if (t == 255) carry += s[255];
        __syncthreads();
    }
}

// ---------------- scan step 3: add block base ----------------
__global__ void k_scan3(int* __restrict__ rowstart, const int* __restrict__ bbase) {
    int i = blockIdx.x * blockDim.x + threadIdx.x;
    if (i < N_NODES) rowstart[i] += bbase[i >> 8];
    if (i == 0) rowstart[N_NODES] = N_EDGES;
}

// ---------------- scatter: edges -> dst-sorted {src, ew}, atomic-free ----------------
__global__ void k_scatter(const void* __restrict__ ei, const float* __restrict__ ew,
                          const int* __restrict__ flag, const int* __restrict__ rowstart,
                          const int* __restrict__ rank, int2* __restrict__ sorted) {
    int e = blockIdx.x * blockDim.x + threadIdx.x;
    if (e >= N_EDGES) return;
    int f = flag[0];
    int s = load_idx(ei, f, e);
    int d = load_idx(ei, f, (long long)N_EDGES + e);
    int pos = rowstart[d] + rank[e];
    sorted[pos] = make_int2(s, __float_as_int(ew[e]));
}

// ---------------- deg (segmented sum of sorted ew) + dinv ----------------
__global__ void k_degdinv(const int2* __restrict__ sorted, const int* __restrict__ rowstart,
                          float* __restrict__ dinv) {
    int n = blockIdx.x * blockDim.x + threadIdx.x;
    if (n >= N_NODES) return;
    int beg = rowstart[n], end = rowstart[n + 1];
    float s = 1.0f;                              // self-loop weight
    for (int e = beg; e < end; ++e) s += __int_as_float(sorted[e].y);
    dinv[n] = rsqrtf(s);                         // always > 0
}

// ---------------- GEMM: h = x @ W  (LDS-tiled, coalesced, reg-blocked) ----------------
#define BM 128
#define BK 64
__global__ __launch_bounds__(256, 3) void k_gemm(const float* __restrict__ x,
                                                 const float* __restrict__ w,
                                                 float* __restrict__ h) {
    __shared__ float xs[BM][BK + 4];   // stride 68
    __shared__ float ws[BK][F_OUT];    // stride 64

    const int t = threadIdx.x;
    const int lane = t & 63;
    const int wv = t >> 6;            // 0..3
    const int rq = lane >> 4;         // 0..3
    const int cq = lane & 15;         // 0..15
    const int row0 = blockIdx.x * BM;

    const int q  = t >> 4;            // 0..15
    const int m4 = (t & 15) << 2;     // 0,4,..,60

    float acc[8][4];
#pragma unroll
    for (int i = 0; i < 8; ++i)
#pragma unroll
        for (int c = 0; c < 4; ++c) acc[i][c] = 0.0f;

    for (int kk0 = 0; kk0 < F_IN; kk0 += BK) {
#pragma unroll
        for (int j = 0; j < 4; ++j) {
            int k = j * 16 + q;
            *(float4*)&ws[k][m4] = *(const float4*)&w[(size_t)(kk0 + k) * F_OUT + m4];
        }
#pragma unroll
        for (int j = 0; j < 8; ++j) {
            int r = j * 16 + q;
            int rg = row0 + r; if (rg > N_NODES - 1) rg = N_NODES - 1;
            *(float4*)&xs[r][m4] = *(const float4*)&x[(size_t)rg * F_IN + kk0 + m4];
        }
        __syncthreads();

#pragma unroll 2
        for (int k4 = 0; k4 < BK; k4 += 4) {
            float4 w0 = *(const float4*)&ws[k4 + 0][cq * 4];
            float4 w1 = *(const float4*)&ws[k4 + 1][cq * 4];
            float4 w2 = *(const float4*)&ws[k4 + 2][cq * 4];
            float4 w3 = *(const float4*)&ws[k4 + 3][cq * 4];
#pragma unroll
            for (int i = 0; i < 8; ++i) {
                int r = wv * 32 + rq + 4 * i;
                float4 xv = *(const float4*)&xs[r][k4];
                acc[i][0] += xv.x * w0.x + xv.y * w1.x + xv.z * w2.x + xv.w * w3.x;
                acc[i][1] += xv.x * w0.y + xv.y * w1.y + xv.z * w2.y + xv.w * w3.y;
                acc[i][2] += xv.x * w0.z + xv.y * w1.z + xv.z * w2.z + xv.w * w3.z;
                acc[i][3] += xv.x * w0.w + xv.y * w1.w + xv.z * w2.w + xv.w * w3.w;
            }
        }
        __syncthreads();
    }

#pragma unroll
    for (int i = 0; i < 8; ++i) {
        int rg = row0 + wv * 32 + rq + 4 * i;
        if (rg < N_NODES)
            *(float4*)&h[(size_t)rg * F_OUT + cq * 4] =
                make_float4(acc[i][0], acc[i][1], acc[i][2], acc[i][3]);
    }
}

// ---------------- aggregation: wave per node, norm inline, fused epilogue ----------------
// out[n] = dinv[n] * sum_e( dinv[src]*ew*h[src] ) + dinv[n]^2*h[n] + bias
__global__ __launch_bounds__(256) void k_agg2(const int2* __restrict__ sorted,
                                              const int* __restrict__ rowstart,
                                              const float* __restrict__ h,
                                              const float* __restrict__ dinv,
                                              const float* __restrict__ bias,
                                              float* __restrict__ out) {
    int lane = threadIdx.x & 63;
    int wid = blockIdx.x * (blockDim.x >> 6) + (threadIdx.x >> 6);
    int nw = gridDim.x * (blockDim.x >> 6);
    float bv = bias[lane];
    for (int n = wid; n < N_NODES; n += nw) {
        int beg = rowstart[n], end = rowstart[n + 1];
        float dn = dinv[n];
        float acc = 0.0f;
        int e = beg;
        for (; e + 1 < end; e += 2) {           // 2 indep gather chains
            int2 m0 = sorted[e];
            int2 m1 = sorted[e + 1];
            float c0 = dinv[m0.x] * __int_as_float(m0.y);   // broadcast gathers
            float c1 = dinv[m1.x] * __int_as_float(m1.y);
            float h0 = h[(size_t)m0.x * F_OUT + lane];
            float h1 = h[(size_t)m1.x * F_OUT + lane];
            acc += c0 * h0 + c1 * h1;
        }
        if (e < end) {
            int2 m = sorted[e];
            acc += dinv[m.x] * __int_as_float(m.y) * h[(size_t)m.x * F_OUT + lane];
        }
        out[(size_t)n * F_OUT + lane] = dn * acc + dn * dn * h[(size_t)n * F_OUT + lane] + bv;
    }
}

extern "C" void kernel_launch(void* const* d_in, const int* in_sizes, int n_in,
                              void* d_out, int out_size, void* d_ws, size_t ws_size,
                              hipStream_t stream) {
    const float* x    = (const float*)d_in[0];
    const float* w    = (const float*)d_in[1];
    const float* bias = (const float*)d_in[2];
    const void*  ei   = d_in[3];
    const float* ew   = (const float*)d_in[4];
    float* out = (float*)d_out;

    char* p = (char*)d_ws;
    int*   flag     = (int*)p;                       p += 256;
    float* dinv     = (float*)p;                     p += 400000;
    int*   cnt      = (int*)p;                       p += 400000;
    int*   rowstart = (int*)p;                       p += 400128;   // N+1, padded
    int*   bsum     = (int*)p;                       p += 2048;
    int*   bbase    = (int*)p;                       p += 2048;
    int*   rank     = (int*)p;                       p += (size_t)N_EDGES * 4;
    float* h        = (float*)p;                     p += (size_t)N_NODES * F_OUT * 4;
    int2*  sorted   = (int2*)p;                      // E * 8 B

    k_detect  <<<1, 64, 0, stream>>>((const int*)ei, flag);
    k_zero_cnt<<<(N_NODES + 255) / 256, 256, 0, stream>>>(cnt);
    k_rank    <<<(N_EDGES + 255) / 256, 256, 0, stream>>>(ei, flag, cnt, rank);
    k_gemm    <<<(N_NODES + BM - 1) / BM, 256, 0, stream>>>(x, w, h);
    k_scan1   <<<NB_SCAN, 256, 0, stream>>>(cnt, rowstart, bsum);
    k_scan2   <<<1, 256, 0, stream>>>(bsum, bbase);
    k_scan3   <<<(N_NODES + 255) / 256, 256, 0, stream>>>(rowstart, bbase);
    k_scatter <<<(N_EDGES + 255) / 256, 256, 0, stream>>>(ei, ew, flag, rowstart, rank, sorted);
    k_degdinv <<<(N_NODES + 255) / 256, 256, 0, stream>>>(sorted, rowstart, dinv);
    k_agg2    <<<2048, 256, 0, stream>>>(sorted, rowstart, h, dinv, bias, out);
}